// Round 14
// baseline (995.528 us; speedup 1.0000x reference)
//
#include <hip/hip_runtime.h>
#include <hip/hip_cooperative_groups.h>

namespace cg = cooperative_groups;

// GraphNeuralNetwork: 4 layers of gather(src)*w -> scatter_add(dst) -> +bias -> relu
// B=256, N=8192, E=262144 (2^18), fp32 in/out.
// Round 13: single cooperative kernel, retried. r10's crash is now attributed to
// the bcur half-zeroing bug (proven+fixed in r12, which passes); phase bodies here
// are r12's verbatim, incl. the LDS-metadata gather. Fusion removes 8 launch
// boundaries (~1-2us each + short-kernel tails) and surfaces gather counters.
// 1024 blocks x 256 thr, 20.5KB LDS, launch_bounds(256,4) -> 4 blocks/CU.

static constexpr int BATCH = 256;
static constexpr int NN    = 8192;
static constexpr int NE    = 262144;   // 2^18
static constexpr int NL    = 4;
static constexpr int NBUK  = 128;      // coarse buckets per layer (64 dst rows each)
static constexpr int BCAP  = 3072;     // staging capacity per bucket
static constexpr int CHUNK = 2048;     // edges per build vblock

__device__ inline unsigned bf16rne(float f) {  // f32 -> bf16 bits, round-nearest-even
  unsigned u = __float_as_uint(f);
  return (u + 0x7fffu + ((u >> 16) & 1u)) >> 16;
}
__device__ inline float bf16tof(unsigned us) { return __uint_as_float(us << 16); }
__device__ inline float blo(unsigned u) { return __uint_as_float(u << 16); }
__device__ inline float bhi(unsigned u) { return __uint_as_float(u & 0xffff0000u); }

__global__ __launch_bounds__(256, 4) void fused_k(
    const float* __restrict__ x, const float* __restrict__ weights,
    const float* __restrict__ bias, const int* __restrict__ esrc,
    const int* __restrict__ edst, float* __restrict__ out,
    float2* __restrict__ csr, int* __restrict__ rp, int* __restrict__ bcur,
    uint2* __restrict__ stag, ushort* __restrict__ actA, ushort* __restrict__ actB) {
  cg::grid_group grid = cg::this_grid();
  __shared__ int si[640];                    // 2.5KB scan/count scratch
  __shared__ uint2 s_ebuf[CHUNK];            // 16KB; reused as tile / smeta
  __shared__ unsigned char s_bkt[CHUNK];     // 2KB
  const int t   = threadIdx.x;
  const int bid = blockIdx.x;

  // ---- phase 0: zero ALL 512 bucket cursors (grid-strided, r12 fix) ----
  for (int i = bid * 256 + t; i < NL * NBUK; i += 1024 * 256) bcur[i] = 0;
  grid.sync();

  // ---- phase 1: partition edges into coarse buckets (512 vblocks) ----
  if (bid < 512) {
    int *cnt = si, *sc = si + 128, *loff = si + 256, *gbase = si + 384, *lcur = si + 512;
    int l = bid >> 7;                        // 128 vblocks per layer
    size_t e0 = (size_t)bid * CHUNK;
    if (t < NBUK) cnt[t] = 0;
    __syncthreads();
    int es[8], ed[8]; float ew[8];
#pragma unroll
    for (int k = 0; k < 8; ++k) {
      size_t e = e0 + t + k * 256;
      es[k] = esrc[e]; ed[k] = edst[e]; ew[k] = weights[e];
      atomicAdd(&cnt[ed[k] >> 6], 1);
    }
    __syncthreads();
    if (t < NBUK) sc[t] = cnt[t];
    __syncthreads();
    for (int off = 1; off < NBUK; off <<= 1) {   // inclusive scan
      int v = 0;
      if (t < NBUK && t >= off) v = sc[t - off];
      __syncthreads();
      if (t < NBUK) sc[t] += v;
      __syncthreads();
    }
    if (t < NBUK) {
      int excl = sc[t] - cnt[t];
      loff[t] = excl; lcur[t] = excl;
      gbase[t] = atomicAdd(&bcur[(l << 7) + t], cnt[t]);  // 1 atomic/(vblock,bucket)
    }
    __syncthreads();
#pragma unroll
    for (int k = 0; k < 8; ++k) {
      int b = ed[k] >> 6;
      int p = atomicAdd(&lcur[b], 1);        // LDS atomic, block-local ordering
      s_ebuf[p] = make_uint2((unsigned)es[k] | ((unsigned)(ed[k] & 63) << 16),
                             __float_as_uint(ew[k]));
      s_bkt[p]  = (unsigned char)b;
    }
    __syncthreads();
#pragma unroll
    for (int k = 0; k < 8; ++k) {            // coalesced run writes
      int i = t + k * 256;
      int b = s_bkt[i];
      int gp = gbase[b] + (i - loff[b]);
      if ((unsigned)gp < BCAP)               // rejects negative AND overflow
        stag[(size_t)((l << 7) + b) * BCAP + gp] = s_ebuf[i];
    }
  }
  grid.sync();

  // ---- phase 2: place buckets -> csr segments + row_ptr (512 vblocks) ----
  // Streams staging from global twice (count, then scatter) — L2-hot re-read.
  if (bid < 512) {
    int *bc = si, *bsc = si + 128, *cnt = si + 256, *sc64 = si + 320, *lcur = si + 384;
    int gb = bid, l = gb >> 7, b = gb & 127;
    if (t < NBUK) { bc[t] = min(bcur[(l << 7) + t], BCAP); bsc[t] = bc[t]; }
    if (t < 64) cnt[t] = 0;
    __syncthreads();
    for (int off = 1; off < NBUK; off <<= 1) {   // scan bucket counts
      int v = 0;
      if (t < NBUK && t >= off) v = bsc[t - off];
      __syncthreads();
      if (t < NBUK) bsc[t] += v;
      __syncthreads();
    }
    int n = bc[b], seg = bsc[b] - bc[b];
    const uint2* sg = stag + (size_t)gb * BCAP;
    for (int i = t; i < n; i += 256)             // pass A: count rows
      atomicAdd(&cnt[(sg[i].x >> 16) & 63], 1);
    __syncthreads();
    if (t < 64) sc64[t] = cnt[t];
    __syncthreads();
    for (int off = 1; off < 64; off <<= 1) {     // scan 64 row counts
      int v = 0;
      if (t < 64 && t >= off) v = sc64[t - off];
      __syncthreads();
      if (t < 64) sc64[t] += v;
      __syncthreads();
    }
    if (t < 64) {
      int excl = sc64[t] - cnt[t];
      lcur[t] = excl;
      rp[l * (NN + 1) + (b << 6) + t] = seg + excl;
    }
    if (b == 127 && t == 64) rp[l * (NN + 1) + NN] = bsc[127];
    __syncthreads();
    for (int i = t; i < n; i += 256) {           // pass B: scatter
      uint2 r = sg[i];
      int p = atomicAdd(&lcur[(r.x >> 16) & 63], 1);
      csr[(size_t)l * NE + seg + p] =
          make_float2(__int_as_float((int)(r.x & 0xffffu)), __uint_as_float(r.y));
    }
  }
  grid.sync();

  // ---- phase 3: transpose x [B,N] f32 -> actA [N,B] bf16 (2048 vtiles) ----
  {
    float (*tile)[33] = (float(*)[33])s_ebuf;
    int tx = t & 31, ty = t >> 5;
    for (int vt = bid; vt < 2048; vt += 1024) {
      int c0 = (vt & 255) * 32, r0 = (vt >> 8) * 32;   // c0 over N, r0 over B
      __syncthreads();
      for (int i = ty; i < 32; i += 8)
        tile[i][tx] = x[(size_t)(r0 + i) * NN + (c0 + tx)];
      __syncthreads();
      for (int i = ty; i < 32; i += 8)
        actA[(size_t)(c0 + i) * BATCH + (r0 + tx)] = (ushort)bf16rne(tile[tx][i]);
    }
  }
  grid.sync();

  // ---- phase 4: 4 gather layers (r12 LDS-metadata body), grid.sync between ----
  {
    unsigned long long* smeta = (unsigned long long*)s_ebuf;  // [4][64], 2KB
    int wid  = t >> 6;
    int lane = t & 63;
    int half = lane >> 5;
    int l32  = lane & 31;
    const unsigned long long* mp = &smeta[wid * 64 + half];
    for (int l = 0; l < NL; ++l) {
      const ushort* ain  = (l & 1) ? actB : actA;
      ushort*       aout = (l & 1) ? actA : actB;
      const float2* csrl = csr + (size_t)l * NE;
      const int*    rpl  = rp + l * (NN + 1);
      const float*  bl   = bias + l * NN;
      const ushort* actc = ain + l32 * 8;
      for (int vb = bid; vb < 2048; vb += 1024) {
        int row = vb * 4 + wid;
        int k0 = rpl[row], k1 = rpl[row + 1];
        float4 accA = make_float4(0.f, 0.f, 0.f, 0.f);
        float4 accB = make_float4(0.f, 0.f, 0.f, 0.f);
        for (int kc = k0; kc < k1; kc += 64) {
          int nk = k1 - kc;
          if (nk > 64) nk = 64;
          int ksel = lane < nk ? lane : 0;           // guarded coalesced load
          unsigned long long mu = __builtin_nontemporal_load(
              (const unsigned long long*)(csrl + kc + ksel));
          if (lane >= nk) mu = 0ull;                 // sanitize: s=0, wt=0
          smeta[wid * 64 + lane] = mu;               // per-wave slot; in-order DS
          int npair = (nk + 1) >> 1;
#pragma unroll 8
          for (int j = 0; j < npair; ++j) {
            unsigned long long m = mp[2 * j];        // ds_read_b64, imm offset
            int   s  = (int)(m & 0xffffffffu);
            float wt = __uint_as_float((unsigned)(m >> 32));
            uint4 v = *(const uint4*)(actc + (size_t)s * BATCH);
            accA.x += wt * blo(v.x); accA.y += wt * bhi(v.x);
            accA.z += wt * blo(v.y); accA.w += wt * bhi(v.y);
            accB.x += wt * blo(v.z); accB.y += wt * bhi(v.z);
            accB.z += wt * blo(v.w); accB.w += wt * bhi(v.w);
          }
        }
        accA.x += __shfl(accA.x, lane ^ 32); accA.y += __shfl(accA.y, lane ^ 32);
        accA.z += __shfl(accA.z, lane ^ 32); accA.w += __shfl(accA.w, lane ^ 32);
        accB.x += __shfl(accB.x, lane ^ 32); accB.y += __shfl(accB.y, lane ^ 32);
        accB.z += __shfl(accB.z, lane ^ 32); accB.w += __shfl(accB.w, lane ^ 32);
        if (half == 0) {
          float b = bl[row];
          uint4 o;
          o.x = bf16rne(fmaxf(accA.x + b, 0.f)) | (bf16rne(fmaxf(accA.y + b, 0.f)) << 16);
          o.y = bf16rne(fmaxf(accA.z + b, 0.f)) | (bf16rne(fmaxf(accA.w + b, 0.f)) << 16);
          o.z = bf16rne(fmaxf(accB.x + b, 0.f)) | (bf16rne(fmaxf(accB.y + b, 0.f)) << 16);
          o.w = bf16rne(fmaxf(accB.z + b, 0.f)) | (bf16rne(fmaxf(accB.w + b, 0.f)) << 16);
          *(uint4*)(aout + (size_t)row * BATCH + l32 * 8) = o;
        }
      }
      grid.sync();
    }
  }

  // ---- phase 5: transpose actA [N,B] bf16 -> out [B,N] f32 (NL even -> actA) ----
  {
    float (*tile)[33] = (float(*)[33])s_ebuf;
    int tx = t & 31, ty = t >> 5;
    for (int vt = bid; vt < 2048; vt += 1024) {
      int c0 = (vt & 7) * 32, r0 = (vt >> 3) * 32;     // c0 over B, r0 over N
      __syncthreads();
      for (int i = ty; i < 32; i += 8)
        tile[i][tx] = bf16tof(actA[(size_t)(r0 + i) * BATCH + (c0 + tx)]);
      __syncthreads();
      for (int i = ty; i < 32; i += 8)
        out[(size_t)(c0 + i) * NN + (r0 + tx)] = tile[tx][i];
    }
  }
}

extern "C" void kernel_launch(void* const* d_in, const int* in_sizes, int n_in,
                              void* d_out, int out_size, void* d_ws, size_t ws_size,
                              hipStream_t stream) {
  const float* x       = (const float*)d_in[0];  // [B, N]
  const float* weights = (const float*)d_in[1];  // [L, E]
  const float* bias    = (const float*)d_in[2];  // [L, N]
  const int*   esrc    = (const int*)d_in[3];    // [L, E]
  const int*   edst    = (const int*)d_in[4];    // [L, E]
  float*       out     = (float*)d_out;          // [B, N]

  // workspace (un-aliased; ~28.2 MB total)
  char* p = (char*)d_ws;
  float2* csr     = (float2*)p; p += (size_t)NL * NE * 8;            // 8 MB
  int*    row_ptr = (int*)p;    p += (size_t)NL * (NN + 1) * 4;
  int*    bcur    = (int*)p;    p += (size_t)NL * NBUK * 4;
  uint2*  stag    = (uint2*)p;  p += (size_t)NL * NBUK * BCAP * 8;   // 12 MB
  ushort* actA    = (ushort*)p; p += (size_t)NN * BATCH * 2;         // 4 MB
  ushort* actB    = (ushort*)p;                                      // 4 MB

  void* kargs[] = {&x, &weights, &bias, &esrc, &edst, &out,
                   &csr, &row_ptr, &bcur, &stag, &actA, &actB};
  hipLaunchCooperativeKernel((void*)fused_k, dim3(1024), dim3(256),
                             kargs, 0, stream);
}

// Round 15
// 126.438 us; speedup vs baseline: 7.8736x; 7.8736x over previous
//
#include <hip/hip_runtime.h>

// GraphNeuralNetwork: 4 layers of gather(src)*w -> scatter_add(dst) -> +bias -> relu
// B=256, N=8192, E=262144 (2^18), fp32 in/out.
// Round 14: r12 base (90.1us; cooperative fusion closed — r13 grid.sync cost
// ~115us each). Gather is L3-BW-bound (134MB/13.5us ~= 9.9TB/s, zero L2 reuse).
// New gather: XCD-PINNED batch slices at constant instruction efficiency.
// slice = blockIdx&3 (4 slices x 64 cols, 1MB each); round-robin block->XCD
// means XCD x only touches slice x&3 -> 1MB hot set resident in its 4MB L2,
// ~32x line reuse. 8 lanes x 16B per edge (8 edges/wave-iter, same B/instr as
// r12), LDS-staged sanitized metadata, 4 rows/wave, 3-step xor slot-reduce.

static constexpr int BATCH = 256;
static constexpr int NN    = 8192;
static constexpr int NE    = 262144;   // 2^18
static constexpr int NL    = 4;
static constexpr int NBUK  = 128;      // coarse buckets per layer (64 dst rows each)
static constexpr int BCAP  = 3072;     // staging capacity per bucket
static constexpr int CHUNK = 2048;     // edges per block in pass 1

__device__ inline unsigned bf16rne(float f) {  // f32 -> bf16 bits, round-nearest-even
  unsigned u = __float_as_uint(f);
  return (u + 0x7fffu + ((u >> 16) & 1u)) >> 16;
}
__device__ inline float bf16tof(unsigned us) { return __uint_as_float(us << 16); }
__device__ inline float blo(unsigned u) { return __uint_as_float(u << 16); }
__device__ inline float bhi(unsigned u) { return __uint_as_float(u & 0xffff0000u); }

// ---- f32 [B,N] -> bf16 [N,B]; block (0,0) also zeroes ALL 512 bcur entries ----
__global__ void transpose_in_k(const float* __restrict__ in, ushort* __restrict__ out,
                               int* __restrict__ bcur) {
  if (blockIdx.x == 0 && blockIdx.y == 0) {
    int t = threadIdx.y * 32 + threadIdx.x;          // 256 threads
    for (int i = t; i < NL * NBUK; i += 256) bcur[i] = 0;   // 512 entries
  }
  __shared__ float tile[32][33];
  int c0 = blockIdx.x * 32, r0 = blockIdx.y * 32;   // c0 over N, r0 over B
  int tx = threadIdx.x, ty = threadIdx.y;
#pragma unroll
  for (int i = ty; i < 32; i += 8)
    tile[i][tx] = in[(size_t)(r0 + i) * NN + (c0 + tx)];
  __syncthreads();
#pragma unroll
  for (int i = ty; i < 32; i += 8)
    out[(size_t)(c0 + i) * BATCH + (r0 + tx)] = (ushort)bf16rne(tile[tx][i]);
}

// ---- bf16 [N,B] -> f32 [B,N] ----
__global__ void transpose_out_k(const ushort* __restrict__ in, float* __restrict__ out) {
  __shared__ float tile[32][33];
  int c0 = blockIdx.x * 32, r0 = blockIdx.y * 32;   // c0 over B, r0 over N
  int tx = threadIdx.x, ty = threadIdx.y;
#pragma unroll
  for (int i = ty; i < 32; i += 8)
    tile[i][tx] = bf16tof(in[(size_t)(r0 + i) * BATCH + (c0 + tx)]);
  __syncthreads();
#pragma unroll
  for (int i = ty; i < 32; i += 8)
    out[(size_t)(c0 + i) * NN + (r0 + tx)] = tile[tx][i];
}

// ---- Pass 1: partition edges into coarse buckets, block-ordered coalesced writes ----
__global__ void part_k(const int* __restrict__ src, const int* __restrict__ dst,
                       const float* __restrict__ w, int* __restrict__ bcur,
                       uint2* __restrict__ stag) {
  __shared__ int cnt[NBUK], sc[NBUK], loff[NBUK], gbase[NBUK], lcur[NBUK];
  __shared__ uint2 ebuf[CHUNK];
  __shared__ unsigned char bkt[CHUNK];
  int t = threadIdx.x;
  int l = blockIdx.x >> 7;                 // 128 blocks per layer
  size_t e0 = (size_t)blockIdx.x * CHUNK;
  if (t < NBUK) cnt[t] = 0;
  __syncthreads();
  int es[8], ed[8]; float ew[8];
#pragma unroll
  for (int k = 0; k < 8; ++k) {
    size_t e = e0 + t + k * 256;
    es[k] = src[e]; ed[k] = dst[e]; ew[k] = w[e];
    atomicAdd(&cnt[ed[k] >> 6], 1);
  }
  __syncthreads();
  if (t < NBUK) sc[t] = cnt[t];
  __syncthreads();
  for (int off = 1; off < NBUK; off <<= 1) {   // inclusive scan (all threads barrier)
    int v = 0;
    if (t < NBUK && t >= off) v = sc[t - off];
    __syncthreads();
    if (t < NBUK) sc[t] += v;
    __syncthreads();
  }
  if (t < NBUK) {
    int excl = sc[t] - cnt[t];
    loff[t] = excl;
    lcur[t] = excl;
    gbase[t] = atomicAdd(&bcur[(l << 7) + t], cnt[t]);   // one atomic per (block,bucket)
  }
  __syncthreads();
#pragma unroll
  for (int k = 0; k < 8; ++k) {
    int b = ed[k] >> 6;
    int p = atomicAdd(&lcur[b], 1);          // LDS atomic, block-local ordering
    ebuf[p] = make_uint2((unsigned)es[k] | ((unsigned)(ed[k] & 63) << 16),
                         __float_as_uint(ew[k]));
    bkt[p]  = (unsigned char)b;
  }
  __syncthreads();
#pragma unroll
  for (int k = 0; k < 8; ++k) {              // coalesced run writes (avg 16-edge runs)
    int i = t + k * 256;
    int b = bkt[i];
    int gp = gbase[b] + (i - loff[b]);
    if ((unsigned)gp < BCAP)                 // rejects negative AND overflow
      stag[(size_t)((l << 7) + b) * BCAP + gp] = ebuf[i];
  }
}

// ---- Pass 2: one block per bucket -> final csr segment + row_ptr ----
__global__ void place_k(const uint2* __restrict__ stag, const int* __restrict__ bcur,
                        float2* __restrict__ csr, int* __restrict__ rp) {
  __shared__ int bc[NBUK], bsc[NBUK];
  __shared__ int cnt[64], sc64[64], lcur[64];
  __shared__ uint2 ebuf[BCAP];
  int t = threadIdx.x;
  int gb = blockIdx.x, l = gb >> 7, b = gb & 127;
  if (t < NBUK) { bc[t] = min(bcur[(l << 7) + t], BCAP); bsc[t] = bc[t]; }
  if (t < 64) cnt[t] = 0;
  __syncthreads();
  for (int off = 1; off < NBUK; off <<= 1) {   // inclusive scan of bucket counts
    int v = 0;
    if (t < NBUK && t >= off) v = bsc[t - off];
    __syncthreads();
    if (t < NBUK) bsc[t] += v;
    __syncthreads();
  }
  int n   = bc[b];
  int seg = bsc[b] - bc[b];                    // exclusive base within layer csr
  for (int i = t; i < n; i += 256)             // coalesced staging read
    ebuf[i] = stag[(size_t)gb * BCAP + i];
  __syncthreads();
  for (int i = t; i < n; i += 256)
    atomicAdd(&cnt[(ebuf[i].x >> 16) & 63], 1);
  __syncthreads();
  if (t < 64) sc64[t] = cnt[t];
  __syncthreads();
  for (int off = 1; off < 64; off <<= 1) {     // inclusive scan of 64 row counts
    int v = 0;
    if (t < 64 && t >= off) v = sc64[t - off];
    __syncthreads();
    if (t < 64) sc64[t] += v;
    __syncthreads();
  }
  if (t < 64) {
    int excl = sc64[t] - cnt[t];
    lcur[t] = excl;
    rp[l * (NN + 1) + (b << 6) + t] = seg + excl;
  }
  if (b == 127 && t == 65) rp[l * (NN + 1) + NN] = bsc[127];  // layer total (== NE)
  __syncthreads();
  for (int i = t; i < n; i += 256) {           // scatter within 16KB segment (L2 combines)
    uint2 r = ebuf[i];
    int p = atomicAdd(&lcur[(r.x >> 16) & 63], 1);
    csr[(size_t)l * NE + seg + p] =
        make_float2(__int_as_float((int)(r.x & 0xffffu)), __uint_as_float(r.y));
  }
}

// ---- per-layer gather: XCD-pinned 64-col slices ----
// slice = blockIdx&3 -> XCD x (round-robin bid%8) only sees slice x&3: 1MB act
// hot set resident in local L2. Wave = 4 rows x 1 slice. Per edge: 8 lanes x
// 16B (slot = lane>>3 picks edge, q = lane&7 picks col octet). Metadata chunk
// staged in per-wave LDS slot, sanitized {s=0,wt=0}; 3-step xor slot-reduce.
__global__ __launch_bounds__(256) void
gather_k(const ushort* __restrict__ act, ushort* __restrict__ out,
         const float2* __restrict__ csr, const int* __restrict__ rp,
         const float* __restrict__ bias) {
  __shared__ unsigned long long smeta[4][64];      // 512B per wave
  int wid   = threadIdx.x >> 6;
  int lane  = threadIdx.x & 63;
  int slot  = lane >> 3;                           // edge slot 0..7
  int q     = lane & 7;                            // col octet within slice
  int slice = blockIdx.x & 3;
  int rbase = ((blockIdx.x >> 2) * 4 + wid) * 4;   // 4 rows per wave
  const ushort* actc = act + slice * 64 + q * 8;
  const unsigned long long* mp = &smeta[wid][slot];
  for (int r = 0; r < 4; ++r) {
    int row = rbase + r;
    int k0 = rp[row], k1 = rp[row + 1];
    float a0 = 0.f, a1 = 0.f, a2 = 0.f, a3 = 0.f;
    float a4 = 0.f, a5 = 0.f, a6 = 0.f, a7 = 0.f;
    for (int kc = k0; kc < k1; kc += 64) {
      int nk = k1 - kc;
      if (nk > 64) nk = 64;
      int ksel = lane < nk ? lane : 0;             // guarded coalesced load
      unsigned long long mu =
          __builtin_nontemporal_load((const unsigned long long*)(csr + kc + ksel));
      if (lane >= nk) mu = 0ull;                   // sanitize: s=0, wt=0
      smeta[wid][lane] = mu;                       // per-wave slot; in-order DS
      int niter = (nk + 7) >> 3;
#pragma unroll 4
      for (int j = 0; j < niter; ++j) {
        unsigned long long m = mp[j * 8];          // ds_read_b64, imm offset 64j
        int   s  = (int)(m & 0xffffffffu);
        float wt = __uint_as_float((unsigned)(m >> 32));
        uint4 v = *(const uint4*)(actc + (size_t)s * BATCH);
        a0 += wt * blo(v.x); a1 += wt * bhi(v.x);
        a2 += wt * blo(v.y); a3 += wt * bhi(v.y);
        a4 += wt * blo(v.z); a5 += wt * bhi(v.z);
        a6 += wt * blo(v.w); a7 += wt * bhi(v.w);
      }
    }
    // reduce across the 8 edge slots (xor 8,16,32)
#pragma unroll
    for (int msk = 8; msk < 64; msk <<= 1) {
      a0 += __shfl_xor(a0, msk); a1 += __shfl_xor(a1, msk);
      a2 += __shfl_xor(a2, msk); a3 += __shfl_xor(a3, msk);
      a4 += __shfl_xor(a4, msk); a5 += __shfl_xor(a5, msk);
      a6 += __shfl_xor(a6, msk); a7 += __shfl_xor(a7, msk);
    }
    if (slot == 0) {
      float b = bias[row];
      uint4 o;
      o.x = bf16rne(fmaxf(a0 + b, 0.f)) | (bf16rne(fmaxf(a1 + b, 0.f)) << 16);
      o.y = bf16rne(fmaxf(a2 + b, 0.f)) | (bf16rne(fmaxf(a3 + b, 0.f)) << 16);
      o.z = bf16rne(fmaxf(a4 + b, 0.f)) | (bf16rne(fmaxf(a5 + b, 0.f)) << 16);
      o.w = bf16rne(fmaxf(a6 + b, 0.f)) | (bf16rne(fmaxf(a7 + b, 0.f)) << 16);
      *(uint4*)(out + (size_t)row * BATCH + slice * 64 + q * 8) = o;
    }
  }
}

extern "C" void kernel_launch(void* const* d_in, const int* in_sizes, int n_in,
                              void* d_out, int out_size, void* d_ws, size_t ws_size,
                              hipStream_t stream) {
  const float* x       = (const float*)d_in[0];  // [B, N]
  const float* weights = (const float*)d_in[1];  // [L, E]
  const float* bias    = (const float*)d_in[2];  // [L, N]
  const int*   esrc    = (const int*)d_in[3];    // [L, E]
  const int*   edst    = (const int*)d_in[4];    // [L, E]
  float*       out     = (float*)d_out;          // [B, N]

  // workspace (un-aliased; ~28.2 MB total)
  char* p = (char*)d_ws;
  float2* csr     = (float2*)p; p += (size_t)NL * NE * 8;            // 8 MB
  int*    row_ptr = (int*)p;    p += (size_t)NL * (NN + 1) * 4;
  int*    bcur    = (int*)p;    p += (size_t)NL * NBUK * 4;
  uint2*  stag    = (uint2*)p;  p += (size_t)NL * NBUK * BCAP * 8;   // 12 MB
  ushort* actA    = (ushort*)p; p += (size_t)NN * BATCH * 2;         // 4 MB
  ushort* actB    = (ushort*)p;                                      // 4 MB

  // ---- transpose x (block (0,0) zeroes all 512 bcur entries) ----
  transpose_in_k<<<dim3(NN / 32, BATCH / 32), dim3(32, 8), 0, stream>>>(x, actA, bcur);

  // ---- build CSR ----
  part_k<<<(NL * NE) / CHUNK, 256, 0, stream>>>(esrc, edst, weights, bcur, stag);
  place_k<<<NL * NBUK, 256, 0, stream>>>(stag, bcur, csr, row_ptr);

  for (int l = 0; l < NL; ++l) {
    // grid: 512 row-groups x 4 slices = 2048 blocks; slice = bid&3 (XCD-pinned)
    gather_k<<<2048, 256, 0, stream>>>((l & 1) ? actB : actA,
                                       (l & 1) ? actA : actB,
                                       csr + (size_t)l * NE,
                                       row_ptr + (size_t)l * (NN + 1),
                                       bias + (size_t)l * NN);
  }

  // actA [N,B] bf16 -> out [B,N] f32 (NL even -> result in actA)
  transpose_out_k<<<dim3(BATCH / 32, NN / 32), dim3(32, 8), 0, stream>>>(actA, out);
}

// Round 16
// 107.524 us; speedup vs baseline: 9.2587x; 1.1759x over previous
//
#include <hip/hip_runtime.h>

// GraphNeuralNetwork: 4 layers of gather(src)*w -> scatter_add(dst) -> +bias -> relu
// B=256, N=8192, E=262144 (2^18), fp32 in/out.
// Round 15: r12 base (90.1us; locality attacks 0-for-4, closed). New gather:
// ROW-PAIR per wave. Theory: per-row metadata->LDS dependency forces a
// conservative vmcnt(0) drain each row (variable trip counts), killing act-load
// MLP at every row boundary (8192 drains/layer). Staging BOTH rows' chunks
// before one drain halves drain frequency and doubles the load window (~32
// independent act loads). Both half-waves write in the epilogue (r0/r1).
// launch_bounds(256,8) caps VGPR<=64 -> full 32 waves/CU. Rest = r12 verbatim.

static constexpr int BATCH = 256;
static constexpr int NN    = 8192;
static constexpr int NE    = 262144;   // 2^18
static constexpr int NL    = 4;
static constexpr int NBUK  = 128;      // coarse buckets per layer (64 dst rows each)
static constexpr int BCAP  = 3072;     // staging capacity per bucket
static constexpr int CHUNK = 2048;     // edges per block in pass 1

__device__ inline unsigned bf16rne(float f) {  // f32 -> bf16 bits, round-nearest-even
  unsigned u = __float_as_uint(f);
  return (u + 0x7fffu + ((u >> 16) & 1u)) >> 16;
}
__device__ inline float bf16tof(unsigned us) { return __uint_as_float(us << 16); }
__device__ inline float blo(unsigned u) { return __uint_as_float(u << 16); }
__device__ inline float bhi(unsigned u) { return __uint_as_float(u & 0xffff0000u); }

// ---- f32 [B,N] -> bf16 [N,B]; block (0,0) also zeroes ALL 512 bcur entries ----
__global__ void transpose_in_k(const float* __restrict__ in, ushort* __restrict__ out,
                               int* __restrict__ bcur) {
  if (blockIdx.x == 0 && blockIdx.y == 0) {
    int t = threadIdx.y * 32 + threadIdx.x;          // 256 threads
    for (int i = t; i < NL * NBUK; i += 256) bcur[i] = 0;   // 512 entries
  }
  __shared__ float tile[32][33];
  int c0 = blockIdx.x * 32, r0 = blockIdx.y * 32;   // c0 over N, r0 over B
  int tx = threadIdx.x, ty = threadIdx.y;
#pragma unroll
  for (int i = ty; i < 32; i += 8)
    tile[i][tx] = in[(size_t)(r0 + i) * NN + (c0 + tx)];
  __syncthreads();
#pragma unroll
  for (int i = ty; i < 32; i += 8)
    out[(size_t)(c0 + i) * BATCH + (r0 + tx)] = (ushort)bf16rne(tile[tx][i]);
}

// ---- bf16 [N,B] -> f32 [B,N] ----
__global__ void transpose_out_k(const ushort* __restrict__ in, float* __restrict__ out) {
  __shared__ float tile[32][33];
  int c0 = blockIdx.x * 32, r0 = blockIdx.y * 32;   // c0 over B, r0 over N
  int tx = threadIdx.x, ty = threadIdx.y;
#pragma unroll
  for (int i = ty; i < 32; i += 8)
    tile[i][tx] = bf16tof(in[(size_t)(r0 + i) * BATCH + (c0 + tx)]);
  __syncthreads();
#pragma unroll
  for (int i = ty; i < 32; i += 8)
    out[(size_t)(c0 + i) * NN + (r0 + tx)] = tile[tx][i];
}

// ---- Pass 1: partition edges into coarse buckets, block-ordered coalesced writes ----
__global__ void part_k(const int* __restrict__ src, const int* __restrict__ dst,
                       const float* __restrict__ w, int* __restrict__ bcur,
                       uint2* __restrict__ stag) {
  __shared__ int cnt[NBUK], sc[NBUK], loff[NBUK], gbase[NBUK], lcur[NBUK];
  __shared__ uint2 ebuf[CHUNK];
  __shared__ unsigned char bkt[CHUNK];
  int t = threadIdx.x;
  int l = blockIdx.x >> 7;                 // 128 blocks per layer
  size_t e0 = (size_t)blockIdx.x * CHUNK;
  if (t < NBUK) cnt[t] = 0;
  __syncthreads();
  int es[8], ed[8]; float ew[8];
#pragma unroll
  for (int k = 0; k < 8; ++k) {
    size_t e = e0 + t + k * 256;
    es[k] = src[e]; ed[k] = dst[e]; ew[k] = w[e];
    atomicAdd(&cnt[ed[k] >> 6], 1);
  }
  __syncthreads();
  if (t < NBUK) sc[t] = cnt[t];
  __syncthreads();
  for (int off = 1; off < NBUK; off <<= 1) {   // inclusive scan (all threads barrier)
    int v = 0;
    if (t < NBUK && t >= off) v = sc[t - off];
    __syncthreads();
    if (t < NBUK) sc[t] += v;
    __syncthreads();
  }
  if (t < NBUK) {
    int excl = sc[t] - cnt[t];
    loff[t] = excl;
    lcur[t] = excl;
    gbase[t] = atomicAdd(&bcur[(l << 7) + t], cnt[t]);   // one atomic per (block,bucket)
  }
  __syncthreads();
#pragma unroll
  for (int k = 0; k < 8; ++k) {
    int b = ed[k] >> 6;
    int p = atomicAdd(&lcur[b], 1);          // LDS atomic, block-local ordering
    ebuf[p] = make_uint2((unsigned)es[k] | ((unsigned)(ed[k] & 63) << 16),
                         __float_as_uint(ew[k]));
    bkt[p]  = (unsigned char)b;
  }
  __syncthreads();
#pragma unroll
  for (int k = 0; k < 8; ++k) {              // coalesced run writes (avg 16-edge runs)
    int i = t + k * 256;
    int b = bkt[i];
    int gp = gbase[b] + (i - loff[b]);
    if ((unsigned)gp < BCAP)                 // rejects negative AND overflow
      stag[(size_t)((l << 7) + b) * BCAP + gp] = ebuf[i];
  }
}

// ---- Pass 2: one block per bucket -> final csr segment + row_ptr ----
__global__ void place_k(const uint2* __restrict__ stag, const int* __restrict__ bcur,
                        float2* __restrict__ csr, int* __restrict__ rp) {
  __shared__ int bc[NBUK], bsc[NBUK];
  __shared__ int cnt[64], sc64[64], lcur[64];
  __shared__ uint2 ebuf[BCAP];
  int t = threadIdx.x;
  int gb = blockIdx.x, l = gb >> 7, b = gb & 127;
  if (t < NBUK) { bc[t] = min(bcur[(l << 7) + t], BCAP); bsc[t] = bc[t]; }
  if (t < 64) cnt[t] = 0;
  __syncthreads();
  for (int off = 1; off < NBUK; off <<= 1) {   // inclusive scan of bucket counts
    int v = 0;
    if (t < NBUK && t >= off) v = bsc[t - off];
    __syncthreads();
    if (t < NBUK) bsc[t] += v;
    __syncthreads();
  }
  int n   = bc[b];
  int seg = bsc[b] - bc[b];                    // exclusive base within layer csr
  for (int i = t; i < n; i += 256)             // coalesced staging read
    ebuf[i] = stag[(size_t)gb * BCAP + i];
  __syncthreads();
  for (int i = t; i < n; i += 256)
    atomicAdd(&cnt[(ebuf[i].x >> 16) & 63], 1);
  __syncthreads();
  if (t < 64) sc64[t] = cnt[t];
  __syncthreads();
  for (int off = 1; off < 64; off <<= 1) {     // inclusive scan of 64 row counts
    int v = 0;
    if (t < 64 && t >= off) v = sc64[t - off];
    __syncthreads();
    if (t < 64) sc64[t] += v;
    __syncthreads();
  }
  if (t < 64) {
    int excl = sc64[t] - cnt[t];
    lcur[t] = excl;
    rp[l * (NN + 1) + (b << 6) + t] = seg + excl;
  }
  if (b == 127 && t == 65) rp[l * (NN + 1) + NN] = bsc[127];  // layer total (== NE)
  __syncthreads();
  for (int i = t; i < n; i += 256) {           // scatter within 16KB segment (L2 combines)
    uint2 r = ebuf[i];
    int p = atomicAdd(&lcur[(r.x >> 16) & 63], 1);
    csr[(size_t)l * NE + seg + p] =
        make_float2(__int_as_float((int)(r.x & 0xffffu)), __uint_as_float(r.y));
  }
}

// ---- per-layer gather: TWO adjacent rows per wave ----
// Stage both rows' 64-edge metadata chunks (2 loads, ONE vmcnt region), then
// run both inner loops from LDS: ~32 independent act loads per drain instead
// of ~16 per drain. Epilogue: xor-merge, half 0 writes r0, half 1 writes r1.
__global__ __launch_bounds__(256, 8) void
gather_k(const ushort* __restrict__ act, ushort* __restrict__ out,
         const float2* __restrict__ csr, const int* __restrict__ rp,
         const float* __restrict__ bias) {
  __shared__ unsigned long long smeta[4][2][64];   // per wave: 2 row slots, 1KB
  int wid  = threadIdx.x >> 6;
  int lane = threadIdx.x & 63;
  int half = lane >> 5;
  int l32  = lane & 31;
  int pr   = blockIdx.x * 4 + wid;                 // row-pair index
  int r0   = pr * 2, r1 = r0 + 1;
  int kA = rp[r0], kAe = rp[r0 + 1];
  int kB = kAe,    kBe = rp[r1 + 1];               // contiguous ranges
  float4 aA0 = make_float4(0.f, 0.f, 0.f, 0.f);    // row0 cols l32*8+0..3
  float4 aA1 = make_float4(0.f, 0.f, 0.f, 0.f);    // row0 cols l32*8+4..7
  float4 aB0 = make_float4(0.f, 0.f, 0.f, 0.f);    // row1 cols l32*8+0..3
  float4 aB1 = make_float4(0.f, 0.f, 0.f, 0.f);    // row1 cols l32*8+4..7
  const ushort* actc = act + l32 * 8;
  const unsigned long long* mpA = &smeta[wid][0][half];
  const unsigned long long* mpB = &smeta[wid][1][half];
  while (kA < kAe || kB < kBe) {
    int nkA = kAe - kA; nkA = nkA < 0 ? 0 : (nkA > 64 ? 64 : nkA);
    int nkB = kBe - kB; nkB = nkB < 0 ? 0 : (nkB > 64 ? 64 : nkB);
    if (nkA > 0) {                                 // stage row0 chunk
      int ksel = lane < nkA ? lane : 0;
      unsigned long long mu =
          __builtin_nontemporal_load((const unsigned long long*)(csr + kA + ksel));
      if (lane >= nkA) mu = 0ull;
      smeta[wid][0][lane] = mu;
    }
    if (nkB > 0) {                                 // stage row1 chunk
      int ksel = lane < nkB ? lane : 0;
      unsigned long long mu =
          __builtin_nontemporal_load((const unsigned long long*)(csr + kB + ksel));
      if (lane >= nkB) mu = 0ull;
      smeta[wid][1][lane] = mu;
    }
    int npA = (nkA + 1) >> 1;
    int npB = (nkB + 1) >> 1;
#pragma unroll 8
    for (int j = 0; j < npA; ++j) {
      unsigned long long m = mpA[2 * j];           // ds_read_b64, imm offset
      int   s  = (int)(m & 0xffffffffu);
      float wt = __uint_as_float((unsigned)(m >> 32));
      uint4 v = *(const uint4*)(actc + (size_t)s * BATCH);
      aA0.x += wt * blo(v.x); aA0.y += wt * bhi(v.x);
      aA0.z += wt * blo(v.y); aA0.w += wt * bhi(v.y);
      aA1.x += wt * blo(v.z); aA1.y += wt * bhi(v.z);
      aA1.z += wt * blo(v.w); aA1.w += wt * bhi(v.w);
    }
#pragma unroll 8
    for (int j = 0; j < npB; ++j) {
      unsigned long long m = mpB[2 * j];
      int   s  = (int)(m & 0xffffffffu);
      float wt = __uint_as_float((unsigned)(m >> 32));
      uint4 v = *(const uint4*)(actc + (size_t)s * BATCH);
      aB0.x += wt * blo(v.x); aB0.y += wt * bhi(v.x);
      aB0.z += wt * blo(v.y); aB0.w += wt * bhi(v.y);
      aB1.x += wt * blo(v.z); aB1.y += wt * bhi(v.z);
      aB1.z += wt * blo(v.w); aB1.w += wt * bhi(v.w);
    }
    kA += 64; kB += 64;
  }
  // merge half-wave partials (lane <-> lane^32) for both rows
  aA0.x += __shfl(aA0.x, lane ^ 32); aA0.y += __shfl(aA0.y, lane ^ 32);
  aA0.z += __shfl(aA0.z, lane ^ 32); aA0.w += __shfl(aA0.w, lane ^ 32);
  aA1.x += __shfl(aA1.x, lane ^ 32); aA1.y += __shfl(aA1.y, lane ^ 32);
  aA1.z += __shfl(aA1.z, lane ^ 32); aA1.w += __shfl(aA1.w, lane ^ 32);
  aB0.x += __shfl(aB0.x, lane ^ 32); aB0.y += __shfl(aB0.y, lane ^ 32);
  aB0.z += __shfl(aB0.z, lane ^ 32); aB0.w += __shfl(aB0.w, lane ^ 32);
  aB1.x += __shfl(aB1.x, lane ^ 32); aB1.y += __shfl(aB1.y, lane ^ 32);
  aB1.z += __shfl(aB1.z, lane ^ 32); aB1.w += __shfl(aB1.w, lane ^ 32);
  // half 0 writes row0, half 1 writes row1 — all 64 lanes store
  int    wrow = half ? r1 : r0;
  float4 w0   = half ? aB0 : aA0;
  float4 w1   = half ? aB1 : aA1;
  float  b    = bias[wrow];
  uint4 o;
  o.x = bf16rne(fmaxf(w0.x + b, 0.f)) | (bf16rne(fmaxf(w0.y + b, 0.f)) << 16);
  o.y = bf16rne(fmaxf(w0.z + b, 0.f)) | (bf16rne(fmaxf(w0.w + b, 0.f)) << 16);
  o.z = bf16rne(fmaxf(w1.x + b, 0.f)) | (bf16rne(fmaxf(w1.y + b, 0.f)) << 16);
  o.w = bf16rne(fmaxf(w1.z + b, 0.f)) | (bf16rne(fmaxf(w1.w + b, 0.f)) << 16);
  *(uint4*)(out + (size_t)wrow * BATCH + l32 * 8) = o;
}

extern "C" void kernel_launch(void* const* d_in, const int* in_sizes, int n_in,
                              void* d_out, int out_size, void* d_ws, size_t ws_size,
                              hipStream_t stream) {
  const float* x       = (const float*)d_in[0];  // [B, N]
  const float* weights = (const float*)d_in[1];  // [L, E]
  const float* bias    = (const float*)d_in[2];  // [L, N]
  const int*   esrc    = (const int*)d_in[3];    // [L, E]
  const int*   edst    = (const int*)d_in[4];    // [L, E]
  float*       out     = (float*)d_out;          // [B, N]

  // workspace (un-aliased; ~28.2 MB total)
  char* p = (char*)d_ws;
  float2* csr     = (float2*)p; p += (size_t)NL * NE * 8;            // 8 MB
  int*    row_ptr = (int*)p;    p += (size_t)NL * (NN + 1) * 4;
  int*    bcur    = (int*)p;    p += (size_t)NL * NBUK * 4;
  uint2*  stag    = (uint2*)p;  p += (size_t)NL * NBUK * BCAP * 8;   // 12 MB
  ushort* actA    = (ushort*)p; p += (size_t)NN * BATCH * 2;         // 4 MB
  ushort* actB    = (ushort*)p;                                      // 4 MB

  // ---- transpose x (block (0,0) zeroes all 512 bcur entries) ----
  transpose_in_k<<<dim3(NN / 32, BATCH / 32), dim3(32, 8), 0, stream>>>(x, actA, bcur);

  // ---- build CSR ----
  part_k<<<(NL * NE) / CHUNK, 256, 0, stream>>>(esrc, edst, weights, bcur, stag);
  place_k<<<NL * NBUK, 256, 0, stream>>>(stag, bcur, csr, row_ptr);

  for (int l = 0; l < NL; ++l) {
    // 8192 rows / (4 waves x 2 rows) = 1024 blocks
    gather_k<<<NN / 8, 256, 0, stream>>>((l & 1) ? actB : actA,
                                         (l & 1) ? actA : actB,
                                         csr + (size_t)l * NE,
                                         row_ptr + (size_t)l * (NN + 1),
                                         bias + (size_t)l * NN);
  }

  // actA [N,B] bf16 -> out [B,N] f32 (NL even -> result in actA)
  transpose_out_k<<<dim3(BATCH / 32, NN / 32), dim3(32, 8), 0, stream>>>(actA, out);
}

// Round 17
// 90.198 us; speedup vs baseline: 11.0371x; 1.1921x over previous
//
#include <hip/hip_runtime.h>

// GraphNeuralNetwork: 4 layers of gather(src)*w -> scatter_add(dst) -> +bias -> relu
// B=256, N=8192, E=262144 (2^18), fp32 in/out.
// Round 16: REVERT to round 12 verbatim — best verified config (90.1us).
// Every perturbation tested since regressed: locality 0/4 (r2/r4/r7/r9/r14),
// fusion 0/2 (r10 fault, r13 grid.sync ~115us each), row-pair MLP 0/1 (r15).
// Instruction cuts won twice (r6 edge-pairing, r12 LDS-staged sanitized
// metadata) and are retained here. Gather = 134MB/layer random 512B chunks at
// ~9.9TB/s cache-line fabric rate; bf16 is numerically minimal (fp8 fails the
// 2%-of-max threshold through 4 attenuating layers). Expect ~90us.

static constexpr int BATCH = 256;
static constexpr int NN    = 8192;
static constexpr int NE    = 262144;   // 2^18
static constexpr int NL    = 4;
static constexpr int NBUK  = 128;      // coarse buckets per layer (64 dst rows each)
static constexpr int BCAP  = 3072;     // staging capacity per bucket
static constexpr int CHUNK = 2048;     // edges per block in pass 1

__device__ inline unsigned bf16rne(float f) {  // f32 -> bf16 bits, round-nearest-even
  unsigned u = __float_as_uint(f);
  return (u + 0x7fffu + ((u >> 16) & 1u)) >> 16;
}
__device__ inline float bf16tof(unsigned us) { return __uint_as_float(us << 16); }
__device__ inline float blo(unsigned u) { return __uint_as_float(u << 16); }
__device__ inline float bhi(unsigned u) { return __uint_as_float(u & 0xffff0000u); }

// ---- f32 [B,N] -> bf16 [N,B]; block (0,0) also zeroes ALL 512 bcur entries ----
__global__ void transpose_in_k(const float* __restrict__ in, ushort* __restrict__ out,
                               int* __restrict__ bcur) {
  if (blockIdx.x == 0 && blockIdx.y == 0) {
    int t = threadIdx.y * 32 + threadIdx.x;          // 256 threads
    for (int i = t; i < NL * NBUK; i += 256) bcur[i] = 0;   // 512 entries
  }
  __shared__ float tile[32][33];
  int c0 = blockIdx.x * 32, r0 = blockIdx.y * 32;   // c0 over N, r0 over B
  int tx = threadIdx.x, ty = threadIdx.y;
#pragma unroll
  for (int i = ty; i < 32; i += 8)
    tile[i][tx] = in[(size_t)(r0 + i) * NN + (c0 + tx)];
  __syncthreads();
#pragma unroll
  for (int i = ty; i < 32; i += 8)
    out[(size_t)(c0 + i) * BATCH + (r0 + tx)] = (ushort)bf16rne(tile[tx][i]);
}

// ---- bf16 [N,B] -> f32 [B,N] ----
__global__ void transpose_out_k(const ushort* __restrict__ in, float* __restrict__ out) {
  __shared__ float tile[32][33];
  int c0 = blockIdx.x * 32, r0 = blockIdx.y * 32;   // c0 over B, r0 over N
  int tx = threadIdx.x, ty = threadIdx.y;
#pragma unroll
  for (int i = ty; i < 32; i += 8)
    tile[i][tx] = bf16tof(in[(size_t)(r0 + i) * BATCH + (c0 + tx)]);
  __syncthreads();
#pragma unroll
  for (int i = ty; i < 32; i += 8)
    out[(size_t)(c0 + i) * NN + (r0 + tx)] = tile[tx][i];
}

// ---- Pass 1: partition edges into coarse buckets, block-ordered coalesced writes ----
__global__ void part_k(const int* __restrict__ src, const int* __restrict__ dst,
                       const float* __restrict__ w, int* __restrict__ bcur,
                       uint2* __restrict__ stag) {
  __shared__ int cnt[NBUK], sc[NBUK], loff[NBUK], gbase[NBUK], lcur[NBUK];
  __shared__ uint2 ebuf[CHUNK];
  __shared__ unsigned char bkt[CHUNK];
  int t = threadIdx.x;
  int l = blockIdx.x >> 7;                 // 128 blocks per layer
  size_t e0 = (size_t)blockIdx.x * CHUNK;
  if (t < NBUK) cnt[t] = 0;
  __syncthreads();
  int es[8], ed[8]; float ew[8];
#pragma unroll
  for (int k = 0; k < 8; ++k) {
    size_t e = e0 + t + k * 256;
    es[k] = src[e]; ed[k] = dst[e]; ew[k] = w[e];
    atomicAdd(&cnt[ed[k] >> 6], 1);
  }
  __syncthreads();
  if (t < NBUK) sc[t] = cnt[t];
  __syncthreads();
  for (int off = 1; off < NBUK; off <<= 1) {   // inclusive scan (all threads barrier)
    int v = 0;
    if (t < NBUK && t >= off) v = sc[t - off];
    __syncthreads();
    if (t < NBUK) sc[t] += v;
    __syncthreads();
  }
  if (t < NBUK) {
    int excl = sc[t] - cnt[t];
    loff[t] = excl;
    lcur[t] = excl;
    gbase[t] = atomicAdd(&bcur[(l << 7) + t], cnt[t]);   // one atomic per (block,bucket)
  }
  __syncthreads();
#pragma unroll
  for (int k = 0; k < 8; ++k) {
    int b = ed[k] >> 6;
    int p = atomicAdd(&lcur[b], 1);          // LDS atomic, block-local ordering
    ebuf[p] = make_uint2((unsigned)es[k] | ((unsigned)(ed[k] & 63) << 16),
                         __float_as_uint(ew[k]));
    bkt[p]  = (unsigned char)b;
  }
  __syncthreads();
#pragma unroll
  for (int k = 0; k < 8; ++k) {              // coalesced run writes (avg 16-edge runs)
    int i = t + k * 256;
    int b = bkt[i];
    int gp = gbase[b] + (i - loff[b]);
    if ((unsigned)gp < BCAP)                 // rejects negative AND overflow
      stag[(size_t)((l << 7) + b) * BCAP + gp] = ebuf[i];
  }
}

// ---- Pass 2: one block per bucket -> final csr segment + row_ptr ----
__global__ void place_k(const uint2* __restrict__ stag, const int* __restrict__ bcur,
                        float2* __restrict__ csr, int* __restrict__ rp) {
  __shared__ int bc[NBUK], bsc[NBUK];
  __shared__ int cnt[64], sc64[64], lcur[64];
  __shared__ uint2 ebuf[BCAP];
  int t = threadIdx.x;
  int gb = blockIdx.x, l = gb >> 7, b = gb & 127;
  if (t < NBUK) { bc[t] = min(bcur[(l << 7) + t], BCAP); bsc[t] = bc[t]; }
  if (t < 64) cnt[t] = 0;
  __syncthreads();
  for (int off = 1; off < NBUK; off <<= 1) {   // inclusive scan of bucket counts
    int v = 0;
    if (t < NBUK && t >= off) v = bsc[t - off];
    __syncthreads();
    if (t < NBUK) bsc[t] += v;
    __syncthreads();
  }
  int n   = bc[b];
  int seg = bsc[b] - bc[b];                    // exclusive base within layer csr
  for (int i = t; i < n; i += 256)             // coalesced staging read
    ebuf[i] = stag[(size_t)gb * BCAP + i];
  __syncthreads();
  for (int i = t; i < n; i += 256)
    atomicAdd(&cnt[(ebuf[i].x >> 16) & 63], 1);
  __syncthreads();
  if (t < 64) sc64[t] = cnt[t];
  __syncthreads();
  for (int off = 1; off < 64; off <<= 1) {     // inclusive scan of 64 row counts
    int v = 0;
    if (t < 64 && t >= off) v = sc64[t - off];
    __syncthreads();
    if (t < 64) sc64[t] += v;
    __syncthreads();
  }
  if (t < 64) {
    int excl = sc64[t] - cnt[t];
    lcur[t] = excl;
    rp[l * (NN + 1) + (b << 6) + t] = seg + excl;
  }
  if (b == 127 && t == 65) rp[l * (NN + 1) + NN] = bsc[127];  // layer total (== NE)
  __syncthreads();
  for (int i = t; i < n; i += 256) {           // scatter within 16KB segment (L2 combines)
    uint2 r = ebuf[i];
    int p = atomicAdd(&lcur[(r.x >> 16) & 63], 1);
    csr[(size_t)l * NE + seg + p] =
        make_float2(__int_as_float((int)(r.x & 0xffffu)), __uint_as_float(r.y));
  }
}

// ---- per-layer gather: one wave per dst row; paired edges, LDS metadata ----
// Per 64-edge chunk: one coalesced metadata load, sanitize invalid lanes to
// {s=0,wt=0}, stage to this wave's LDS slot (LDS ops are in-order per wave, no
// barrier). Inner loop: ds_read_b64 at immediate offsets — zero validity logic.
__global__ __launch_bounds__(256) void
gather_k(const ushort* __restrict__ act, ushort* __restrict__ out,
         const float2* __restrict__ csr, const int* __restrict__ rp,
         const float* __restrict__ bias) {
  __shared__ unsigned long long smeta[4][64];      // 512B per wave
  int wid  = threadIdx.x >> 6;
  int row  = blockIdx.x * 4 + wid;                 // 4 waves/block
  int lane = threadIdx.x & 63;
  int half = lane >> 5;
  int l32  = lane & 31;
  int k0 = rp[row], k1 = rp[row + 1];
  float4 accA = make_float4(0.f, 0.f, 0.f, 0.f);   // cols l32*8+0..3
  float4 accB = make_float4(0.f, 0.f, 0.f, 0.f);   // cols l32*8+4..7
  const ushort* actc = act + l32 * 8;
  const unsigned long long* mp = &smeta[wid][half];
  for (int kc = k0; kc < k1; kc += 64) {
    int nk = k1 - kc;
    if (nk > 64) nk = 64;
    int ksel = lane < nk ? lane : 0;               // guarded coalesced load
    unsigned long long mu =
        __builtin_nontemporal_load((const unsigned long long*)(csr + kc + ksel));
    if (lane >= nk) mu = 0ull;                     // sanitize: s=0, wt=0
    smeta[wid][lane] = mu;                         // per-wave slot; in-order DS
    int npair = (nk + 1) >> 1;
#pragma unroll 8
    for (int j = 0; j < npair; ++j) {
      unsigned long long m = mp[2 * j];            // ds_read_b64, imm offset 16j
      int   s  = (int)(m & 0xffffffffu);
      float wt = __uint_as_float((unsigned)(m >> 32));
      uint4 v = *(const uint4*)(actc + (size_t)s * BATCH);
      accA.x += wt * blo(v.x); accA.y += wt * bhi(v.x);
      accA.z += wt * blo(v.y); accA.w += wt * bhi(v.y);
      accB.x += wt * blo(v.z); accB.y += wt * bhi(v.z);
      accB.z += wt * blo(v.w); accB.w += wt * bhi(v.w);
    }
  }
  // merge the two half-wave partial sums (lane <-> lane^32)
  accA.x += __shfl(accA.x, lane ^ 32); accA.y += __shfl(accA.y, lane ^ 32);
  accA.z += __shfl(accA.z, lane ^ 32); accA.w += __shfl(accA.w, lane ^ 32);
  accB.x += __shfl(accB.x, lane ^ 32); accB.y += __shfl(accB.y, lane ^ 32);
  accB.z += __shfl(accB.z, lane ^ 32); accB.w += __shfl(accB.w, lane ^ 32);
  if (half == 0) {
    float b = bias[row];
    uint4 o;
    o.x = bf16rne(fmaxf(accA.x + b, 0.f)) | (bf16rne(fmaxf(accA.y + b, 0.f)) << 16);
    o.y = bf16rne(fmaxf(accA.z + b, 0.f)) | (bf16rne(fmaxf(accA.w + b, 0.f)) << 16);
    o.z = bf16rne(fmaxf(accB.x + b, 0.f)) | (bf16rne(fmaxf(accB.y + b, 0.f)) << 16);
    o.w = bf16rne(fmaxf(accB.z + b, 0.f)) | (bf16rne(fmaxf(accB.w + b, 0.f)) << 16);
    *(uint4*)(out + (size_t)row * BATCH + l32 * 8) = o;
  }
}

extern "C" void kernel_launch(void* const* d_in, const int* in_sizes, int n_in,
                              void* d_out, int out_size, void* d_ws, size_t ws_size,
                              hipStream_t stream) {
  const float* x       = (const float*)d_in[0];  // [B, N]
  const float* weights = (const float*)d_in[1];  // [L, E]
  const float* bias    = (const float*)d_in[2];  // [L, N]
  const int*   esrc    = (const int*)d_in[3];    // [L, E]
  const int*   edst    = (const int*)d_in[4];    // [L, E]
  float*       out     = (float*)d_out;          // [B, N]

  // workspace (un-aliased; ~28.2 MB total)
  char* p = (char*)d_ws;
  float2* csr     = (float2*)p; p += (size_t)NL * NE * 8;            // 8 MB
  int*    row_ptr = (int*)p;    p += (size_t)NL * (NN + 1) * 4;
  int*    bcur    = (int*)p;    p += (size_t)NL * NBUK * 4;
  uint2*  stag    = (uint2*)p;  p += (size_t)NL * NBUK * BCAP * 8;   // 12 MB
  ushort* actA    = (ushort*)p; p += (size_t)NN * BATCH * 2;         // 4 MB
  ushort* actB    = (ushort*)p;                                      // 4 MB

  // ---- transpose x (block (0,0) zeroes all 512 bcur entries) ----
  transpose_in_k<<<dim3(NN / 32, BATCH / 32), dim3(32, 8), 0, stream>>>(x, actA, bcur);

  // ---- build CSR ----
  part_k<<<(NL * NE) / CHUNK, 256, 0, stream>>>(esrc, edst, weights, bcur, stag);
  place_k<<<NL * NBUK, 256, 0, stream>>>(stag, bcur, csr, row_ptr);

  for (int l = 0; l < NL; ++l) {
    gather_k<<<NN / 4, 256, 0, stream>>>((l & 1) ? actB : actA,
                                         (l & 1) ? actA : actB,
                                         csr + (size_t)l * NE,
                                         row_ptr + (size_t)l * (NN + 1),
                                         bias + (size_t)l * NN);
  }

  // actA [N,B] bf16 -> out [B,N] f32 (NL even -> result in actA)
  transpose_out_k<<<dim3(BATCH / 32, NN / 32), dim3(32, 8), 0, stream>>>(actA, out);
}